// Round 4
// baseline (330.999 us; speedup 1.0000x reference)
//
#include <hip/hip_runtime.h>

// GCN on MI355X (gfx950). n=100000, 1.6M edges, D 128/128/64.
// Round 13: kill the part-scatter write amplification (k1 was top at 64us,
// WRITE_SIZE 64MB vs 38MB ideal, FETCH showing RMW of partial lines).
//  - part1: each block scatters edges into its OWN contiguous 64KB region
//    (scatter confined to an L2-resident window -> clean writeback, no RMW),
//    publishes per-(bucket,block) offsets to a bucket-major boffs table.
//    bcur updated with fire-and-forget atomicAdd (no return).
//  - part2: segment-gathers its bucket's 196 segments (avg 21 edges,
//    contiguous) into LDS, then the (row,colbucket) counting sort scatters
//    DIRECTLY into pce's ~33KB bucket window (L2-absorbed), dropping the
//    old sout + stream-out pass.
//  - EPB 4096 -> 8192 (longer segments, smaller boffs, 196 part1 blocks).
// Pipeline: wcvt -> K1[part1||gemm0] -> part2 -> F1 -> F2 -> spmm_out.

typedef unsigned int u32;
typedef unsigned short u16;
typedef __attribute__((ext_vector_type(8))) short bf16x8;
typedef __attribute__((ext_vector_type(4))) float f32x4;

constexpr int NN = 100000;
constexpr int NE = 1600000;
constexpr int PAD = 100352;            // 392 * 256
constexpr int NBUCK = 392;             // buckets of 256 rows
constexpr int BCAP = 4608;             // per-bucket capacity (mean 4082, +8 sigma)
constexpr int EPB = 8192;              // edges per part1 block (64KB region)
constexpr int P1B = (NE + EPB - 1) / EPB;   // 196 part1 blocks
constexpr int G0B = (NN + 63) / 64;         // 1563 gemm0 blocks
constexpr int NCB = 13;                // col buckets of 8192 (99999>>13 = 12)

__device__ __forceinline__ u16 f2bf(float f) {   // RNE round to bf16
    u32 x = __float_as_uint(f);
    x += 0x7fffu + ((x >> 16) & 1u);
    return (u16)(x >> 16);
}

// ---------------------------------------------------------------------------
// Weight fp32 -> bf16 in B-fragment order; also zeroes bcur.
// ---------------------------------------------------------------------------
__device__ __forceinline__ void wfrag_one(const float* __restrict__ W,
                                          u16* __restrict__ Wf, int total, int i)
{
    if (i < total) {
        const int j    = i & 7;
        const int lane = (i >> 3) & 63;
        const int kc   = (i >> 9) & 3;
        const int ct   = i >> 11;
        const int src  = (ct * 16 + (lane & 15)) * 128 + kc * 32 + (lane >> 4) * 8 + j;
        Wf[i] = f2bf(W[src]);
    }
}

__global__ __launch_bounds__(256)
void wcvt_kernel(const float* __restrict__ W0, const float* __restrict__ W1,
                 const float* __restrict__ W2, u16* __restrict__ wf0,
                 u16* __restrict__ wf1, u16* __restrict__ wf2,
                 int* __restrict__ bcur)
{
    const int i = blockIdx.x * 256 + threadIdx.x;
    if (i < 512) bcur[i] = 0;
    wfrag_one(W0, wf0, 128 * 128, i);
    wfrag_one(W1, wf1, 128 * 128, i);
    wfrag_one(W2, wf2, 64 * 128, i);
}

// ---------------------------------------------------------------------------
// K1: blocks [0, P1B) = part1 (block-local bucket partition);
//     blocks [P1B, P1B+G0B) = gemm0 (t0 = x @ W0^T, bf16 MFMA).
// Shared LDS buffer sized for the gemm branch (17408 B).
// ---------------------------------------------------------------------------
__global__ __launch_bounds__(256)
void k1_kernel(const float* __restrict__ x, const u16* __restrict__ Wf,
               u16* __restrict__ Cb,
               const int* __restrict__ erow, const int* __restrict__ ecol,
               const float* __restrict__ eval, int* __restrict__ bcur,
               int2* __restrict__ part, int* __restrict__ boffs)
{
    __shared__ u16 smem[64 * 136];     // gemm: sA/sC; part1: hist/excl/scan
    const int tid = threadIdx.x;

    if ((int)blockIdx.x < P1B) {
        // ---------------- part1 branch ----------------
        int* shist = (int*)smem;       // 512 ints
        int* sexcl = shist + 512;      // 512 ints (excl offsets, then cursors)
        int* sdat  = sexcl + 512;      // 256 ints
        const int blk = blockIdx.x;
        shist[tid] = 0; shist[tid + 256] = 0;
        __syncthreads();

        const int base = blk * EPB;
        #pragma unroll
        for (int j = 0; j < EPB / 256; ++j) {
            const int e = base + j * 256 + tid;
            if (e < NE) atomicAdd(&shist[erow[e] >> 8], 1);
        }
        __syncthreads();

        const int c0 = shist[2 * tid];
        const int c1 = shist[2 * tid + 1];
        if (c0) atomicAdd(&bcur[2 * tid], c0);       // fire-and-forget
        if (c1) atomicAdd(&bcur[2 * tid + 1], c1);
        const int tsum = c0 + c1;
        sdat[tid] = tsum;
        __syncthreads();
        #pragma unroll
        for (int off = 1; off < 256; off <<= 1) {
            const int v = (tid >= off) ? sdat[tid - off] : 0;
            __syncthreads();
            sdat[tid] += v;
            __syncthreads();
        }
        const int excl = sdat[tid] - tsum;
        sexcl[2 * tid]     = excl;
        sexcl[2 * tid + 1] = excl + c0;
        const int total = sdat[255];
        __syncthreads();

        // publish per-(bucket,block) exclusive offsets (bucket-major; L2-abs)
        for (int b = tid; b < NBUCK; b += 256)
            boffs[(size_t)b * P1B + blk] = sexcl[b];
        if (tid == 0) boffs[(size_t)NBUCK * P1B + blk] = total;

        // scatter into the block's OWN 64KB region (L2-resident window)
        #pragma unroll
        for (int j = 0; j < EPB / 256; ++j) {
            const int e = base + j * 256 + tid;
            if (e < NE) {
                const int r = erow[e];
                const int b = r >> 8;
                const int pos = atomicAdd(&sexcl[b], 1);
                part[(size_t)blk * EPB + pos] =
                    make_int2(((r & 255) << 17) | ecol[e], __float_as_int(eval[e]));
            }
        }
        return;
    }

    // ---------------- gemm0 branch ----------------
    constexpr int RS   = 136;
    constexpr int PADW = 136;          // DO=128 + 8
    u16* sA = smem;
    u16* sC = smem;
    const int w    = tid >> 6;
    const int lane = tid & 63;
    const int m    = lane & 15;
    const int q    = lane >> 4;
    const int rowBase = ((int)blockIdx.x - P1B) * 64;

    #pragma unroll
    for (int i = 0; i < 8; ++i) {
        const int g = (i * 256 + tid) * 4;
        const int r = g >> 7, c = g & 127;
        float4 v = make_float4(0.f, 0.f, 0.f, 0.f);
        if (rowBase + r < NN) v = *(const float4*)(x + (size_t)(rowBase + r) * 128 + c);
        u16* d = &sA[r * RS + c];
        d[0] = f2bf(v.x); d[1] = f2bf(v.y); d[2] = f2bf(v.z); d[3] = f2bf(v.w);
    }
    __syncthreads();

    bf16x8 afrag[4];
    #pragma unroll
    for (int kc = 0; kc < 4; ++kc)
        afrag[kc] = *(const bf16x8*)&sA[(w * 16 + m) * RS + kc * 32 + q * 8];
    __syncthreads();

    #pragma unroll
    for (int ct = 0; ct < 8; ++ct) {
        f32x4 acc = {0.f, 0.f, 0.f, 0.f};
        #pragma unroll
        for (int kc = 0; kc < 4; ++kc) {
            const bf16x8 b = *(const bf16x8*)(Wf + (((ct * 4 + kc) * 64) + lane) * 8);
            acc = __builtin_amdgcn_mfma_f32_16x16x32_bf16(afrag[kc], b, acc, 0, 0, 0);
        }
        #pragma unroll
        for (int r = 0; r < 4; ++r)
            sC[(w * 16 + q * 4 + r) * PADW + ct * 16 + m] = f2bf(acc[r]);
    }
    __syncthreads();

    const int g    = lane >> 2;
    const int cb   = (lane & 3) * 32;
    const int grow = rowBase + w * 16 + g;
    if (grow < NN) {
        #pragma unroll
        for (int i = 0; i < 4; ++i) {
            const int4 v = *(const int4*)&sC[(w * 16 + g) * PADW + cb + i * 8];
            *(int4*)(Cb + (size_t)grow * 128 + cb + i * 8) = v;
        }
    }
}

// ---------------------------------------------------------------------------
// part2 (round 13): per 256-row bucket -
//   gb from bcur scan; read this bucket's 196 segment bounds from boffs
//   (coalesced); scan lengths -> LDS positions; segment-gather into sbuf;
//   (row*13+colbucket) histogram + scan -> offs + cursors (global base);
//   single scatter pass DIRECTLY into pce's bucket window (L2-absorbed).
// ---------------------------------------------------------------------------
__global__ __launch_bounds__(256)
void part2_kernel(const int* __restrict__ bcur, const int* __restrict__ boffs,
                  const int2* __restrict__ part,
                  int* __restrict__ offs, int2* __restrict__ pce)
{
    __shared__ int2 sbuf[BCAP];        // 36864 B gathered bucket image
    __shared__ int scnt[256 * NCB];    // 13312 B histogram, then cursors
    __shared__ int sdata[256];
    const int b = blockIdx.x;
    const int tid = threadIdx.x;

    // gb = sum bcur[0..b-1]
    int partial = 0;
    for (int i = tid; i < b; i += 256) partial += bcur[i];
    sdata[tid] = partial;
    __syncthreads();
    #pragma unroll
    for (int off = 128; off > 0; off >>= 1) {
        if (tid < off) sdata[tid] += sdata[tid + off];
        __syncthreads();
    }
    const int gb = sdata[0];
    const int cnt = bcur[b];
    __syncthreads();

    // segment bounds: segment k = part1 block k (k in [0, P1B)); thread tid
    // owns segment tid (tid >= P1B idle). Coalesced reads of rows b, b+1.
    int lo = 0, len = 0;
    if (tid < P1B) {
        lo  = boffs[(size_t)b * P1B + tid];
        len = boffs[(size_t)(b + 1) * P1B + tid] - lo;
    }
    sdata[tid] = len;
    __syncthreads();
    #pragma unroll
    for (int off = 1; off < 256; off <<= 1) {
        const int v = (tid >= off) ? sdata[tid - off] : 0;
        __syncthreads();
        sdata[tid] += v;
        __syncthreads();
    }
    const int dst = sdata[tid] - len;

    // zero histogram while gather is in flight
    #pragma unroll
    for (int j = 0; j < NCB; ++j) scnt[j * 256 + tid] = 0;

    // gather this thread's segment (contiguous global read) into sbuf
    if (tid < P1B && len > 0) {
        const int2* srcp = part + (size_t)tid * EPB + lo;
        for (int i = 0; i < len; ++i) sbuf[dst + i] = srcp[i];
    }
    __syncthreads();

    // histogram over combined keys (row*13 + colbucket) from sbuf
    for (int i = tid; i < cnt; i += 256) {
        const int xk = sbuf[i].x;
        atomicAdd(&scnt[(((u32)xk) >> 17) * NCB + ((xk & 0x1FFFF) >> 13)], 1);
    }
    __syncthreads();

    // per-row serial sum (thread tid owns row tid) + block scan of row totals
    int rsum = 0;
    #pragma unroll
    for (int j = 0; j < NCB; ++j) rsum += scnt[tid * NCB + j];
    sdata[tid] = rsum;
    __syncthreads();
    #pragma unroll
    for (int off = 1; off < 256; off <<= 1) {
        const int v = (tid >= off) ? sdata[tid - off] : 0;
        __syncthreads();
        sdata[tid] += v;
        __syncthreads();
    }
    const int excl = sdata[tid] - rsum;
    offs[b * 256 + tid] = gb + excl;       // global CSR offset

    // histogram -> per-key cursors holding GLOBAL positions
    int run = gb + excl;
    #pragma unroll
    for (int j = 0; j < NCB; ++j) {
        const int c = scnt[tid * NCB + j];
        scnt[tid * NCB + j] = run;
        run += c;
    }
    __syncthreads();

    // single scatter pass directly into pce's bucket window (~33KB, L2-abs)
    for (int i = tid; i < cnt; i += 256) {
        const int2 ev = sbuf[i];
        const int rl = ((u32)ev.x) >> 17;
        const int cb = (ev.x & 0x1FFFF) >> 13;
        const int pos = atomicAdd(&scnt[rl * NCB + cb], 1);
        pce[pos] = make_int2(ev.x & 0x1FFFF, ev.y);
    }
}

// ---------------------------------------------------------------------------
// Gather helpers (bf16 rows, fp32 accumulate).
// ---------------------------------------------------------------------------
template<int LPC>
__device__ __forceinline__ void load_row(const u16* p, u32* u) {
    if constexpr (LPC == 8) {
        const uint4 t = *(const uint4*)p;
        u[0] = t.x; u[1] = t.y; u[2] = t.z; u[3] = t.w;
    } else {
        const uint2 t = *(const uint2*)p;
        u[0] = t.x; u[1] = t.y;
    }
}

template<int LPC>
__device__ __forceinline__ void fma_row(float v, const u32* u, float* a) {
    #pragma unroll
    for (int j = 0; j < LPC / 2; ++j) {
        a[2*j]   = fmaf(v, __uint_as_float(u[j] << 16),         a[2*j]);
        a[2*j+1] = fmaf(v, __uint_as_float(u[j] & 0xffff0000u), a[2*j+1]);
    }
}

// ---------------------------------------------------------------------------
// Fused SpMM+GEMM: cooperative pce window load (16 edges / one 128B load per
// group) + shfl(16) broadcast -> 4-edge quads of back-to-back row loads ->
// relu(+residual) -> LDS A-tile -> mfma vs fragment-ordered Wf -> C store.
// MODE 1 also writes relu'd rows (h1) to Hout for the later residual.
// ---------------------------------------------------------------------------
template<int DO, int MODE>
__global__ __launch_bounds__(256)
void spmm_gemm(const int* __restrict__ offs, const int2* __restrict__ pce,
               const u16* __restrict__ Hb, const u16* __restrict__ Wf,
               const u16* __restrict__ Res, u16* __restrict__ Cb,
               u16* __restrict__ Hout)
{
    constexpr int RS   = 136;
    constexpr int PADW = DO + 8;
    __shared__ u16 smem[16 * 136];
    const int tid = threadIdx.x;
    const int ln  = tid & 15;
    const int rl  = tid >> 4;
    const int row = blockIdx.x * 16 + rl;

    const int s = offs[row];
    const int t = offs[row + 1];
    const u16* hbase = Hb + ln * 8;

    float a0[8], a1[8];
    #pragma unroll
    for (int j = 0; j < 8; ++j) { a0[j] = 0.f; a1[j] = 0.f; }

    for (int e = s; e < t; e += 16) {
        // cooperative load of this row's next 16 edges (one int2 per lane)
        int2 my = make_int2(0, 0);
        if (e + ln < t) my = pce[e + ln];
        const int rem = t - e;
        #pragma unroll
        for (int qd = 0; qd < 4; ++qd) {
            if (qd * 4 < rem) {
                const int c0 = __shfl(my.x, qd * 4 + 0, 16);
                const int v0 = __shfl(my.y, qd * 4 + 0, 16);
                const int c1 = __shfl(my.x, qd * 4 + 1, 16);
                const int v1 = __shfl(my.y, qd * 4 + 1, 16);
                const int c2 = __shfl(my.x, qd * 4 + 2, 16);
                const int v2 = __shfl(my.y, qd * 4 + 2, 16);
                const int c3 = __shfl(my.x, qd * 4 + 3, 16);
                const int v3 = __shfl(my.y, qd * 4 + 3, 16);
                u32 u0[4], u1[4], u2[4], u3[4];
                load_row<8>(hbase + (size_t)c0 * 128, u0);
                load_row<8>(hbase + (size_t)c1 * 128, u1);
                load_row<8>(hbase + (size_t)c2 * 128, u2);
                load_row<8>(hbase + (size_t)c3 * 128, u3);
                fma_row<8>(__int_as_float(v0), u0, a0);
                fma_row<8>(__int_as_float(v1), u1, a1);
                fma_row<8>(__int_as_float(v2), u2, a0);
                fma_row<8>(__int_as_float(v3), u3, a1);
            }
        }
    }
    #pragma unroll
    for (int j = 0; j < 8; ++j) a0[j] = fmaxf(a0[j] + a1[j], 0.f);

    if constexpr (MODE == 2) {
        u32 r[4];
        load_row<8>(Res + (size_t)row * 128 + ln * 8, r);
        #pragma unroll
        for (int j = 0; j < 4; ++j) {
            a0[2*j]   += __uint_as_float(r[j] << 16);
            a0[2*j+1] += __uint_as_float(r[j] & 0xffff0000u);
        }
    }
    u32 o[4];
    #pragma unroll
    for (int j = 0; j < 4; ++j)
        o[j] = (u32)f2bf(a0[2*j]) | ((u32)f2bf(a0[2*j+1]) << 16);
    const uint4 packed = make_uint4(o[0], o[1], o[2], o[3]);
    *(uint4*)&smem[rl * RS + ln * 8] = packed;
    if constexpr (MODE == 1)
        *(uint4*)(Hout + (size_t)row * 128 + ln * 8) = packed;
    __syncthreads();

    constexpr int TPW = DO / 64;
    const int w    = tid >> 6;
    const int lane = tid & 63;
    const int m    = lane & 15;
    const int q    = lane >> 4;

    bf16x8 afrag[4];
    #pragma unroll
    for (int kc = 0; kc < 4; ++kc)
        afrag[kc] = *(const bf16x8*)&smem[m * RS + kc * 32 + q * 8];

    f32x4 acc[TPW];
    #pragma unroll
    for (int tw = 0; tw < TPW; ++tw) {
        const int ct = w * TPW + tw;
        acc[tw] = (f32x4){0.f, 0.f, 0.f, 0.f};
        #pragma unroll
        for (int kc = 0; kc < 4; ++kc) {
            const bf16x8 b = *(const bf16x8*)(Wf + (((ct * 4 + kc) * 64) + lane) * 8);
            acc[tw] = __builtin_amdgcn_mfma_f32_16x16x32_bf16(afrag[kc], b, acc[tw], 0, 0, 0);
        }
    }
    __syncthreads();

    #pragma unroll
    for (int tw = 0; tw < TPW; ++tw) {
        const int ct = w * TPW + tw;
        #pragma unroll
        for (int r = 0; r < 4; ++r)
            smem[(q * 4 + r) * PADW + ct * 16 + m] = f2bf(acc[tw][r]);
    }
    __syncthreads();

    if (DO == 128 || tid < 128) {
        const int g = tid * 8;
        const int r = g / DO;
        const int c = g % DO;
        const int4 v = *(const int4*)&smem[r * PADW + c];
        *(int4*)(Cb + ((size_t)blockIdx.x * 16 + r) * DO + c) = v;
    }
}

// ---------------------------------------------------------------------------
// Final CSR SpMM (layer 3): gather t2 (D=64), cooperative pce + shfl, fp32 out.
// ---------------------------------------------------------------------------
__global__ __launch_bounds__(256)
void spmm_out(const int* __restrict__ offs, const int2* __restrict__ pce,
              const u16* __restrict__ Hb, float* __restrict__ Y)
{
    const int ln  = threadIdx.x & 15;
    const int row = blockIdx.x * 16 + (threadIdx.x >> 4);
    if (row >= NN) return;
    const int s = offs[row];
    const int t = offs[row + 1];
    const u16* hbase = Hb + ln * 4;

    float a0[4], a1[4];
    #pragma unroll
    for (int j = 0; j < 4; ++j) { a0[j] = 0.f; a1[j] = 0.f; }

    for (int e = s; e < t; e += 16) {
        int2 my = make_int2(0, 0);
        if (e + ln < t) my = pce[e + ln];
        const int rem = t - e;
        #pragma unroll
        for (int qd = 0; qd < 4; ++qd) {
            if (qd * 4 < rem) {
                const int c0 = __shfl(my.x, qd * 4 + 0, 16);
                const int v0 = __shfl(my.y, qd * 4 + 0, 16);
                const int c1 = __shfl(my.x, qd * 4 + 1, 16);
                const int v1 = __shfl(my.y, qd * 4 + 1, 16);
                const int c2 = __shfl(my.x, qd * 4 + 2, 16);
                const int v2 = __shfl(my.y, qd * 4 + 2, 16);
                const int c3 = __shfl(my.x, qd * 4 + 3, 16);
                const int v3 = __shfl(my.y, qd * 4 + 3, 16);
                u32 u0[2], u1[2], u2[2], u3[2];
                load_row<4>(hbase + (size_t)c0 * 64, u0);
                load_row<4>(hbase + (size_t)c1 * 64, u1);
                load_row<4>(hbase + (size_t)c2 * 64, u2);
                load_row<4>(hbase + (size_t)c3 * 64, u3);
                fma_row<4>(__int_as_float(v0), u0, a0);
                fma_row<4>(__int_as_float(v1), u1, a1);
                fma_row<4>(__int_as_float(v2), u2, a0);
                fma_row<4>(__int_as_float(v3), u3, a1);
            }
        }
    }
    #pragma unroll
    for (int j = 0; j < 4; ++j) a0[j] += a1[j];
    *(float4*)(Y + (size_t)row * 64 + ln * 4) = make_float4(a0[0], a0[1], a0[2], a0[3]);
}

extern "C" void kernel_launch(void* const* d_in, const int* in_sizes, int n_in,
                              void* d_out, int out_size, void* d_ws, size_t ws_size,
                              hipStream_t stream) {
    const float* x    = (const float*)d_in[0];
    const int*   erow = (const int*)  d_in[1];
    const int*   ecol = (const int*)  d_in[2];
    const float* eval = (const float*)d_in[3];
    const float* W0   = (const float*)d_in[4];
    const float* W1   = (const float*)d_in[5];
    const float* W2   = (const float*)d_in[6];
    float* out = (float*)d_out;

    char* p = (char*)d_ws;
    const size_t BUFB = (size_t)NN * 128 * sizeof(u16);   // 25.6 MB
    u16* t0b  = (u16*)p;  p += BUFB;     // t0; reused for t2 (t0 dead by then)
    u16* t1b  = (u16*)p;  p += BUFB;
    u16* h1b  = (u16*)p;  p += BUFB;
    u16* wf0  = (u16*)p;  p += 128 * 128 * 2;
    u16* wf1  = (u16*)p;  p += 128 * 128 * 2;
    u16* wf2  = (u16*)p;  p += 64 * 128 * 2;
    int* bcur   = (int*)p; p += 512 * 4;
    int* boffs  = (int*)p; p += (size_t)(NBUCK + 1) * P1B * 4;  // 308 KB
    int* offs   = (int*)p; p += ((size_t)PAD + 256) * 4;
    int2* part  = (int2*)p; p += (size_t)P1B * EPB * 8;   // 12.85 MB
    int2* pce   = (int2*)p;                               // 12.8 MB

    const dim3 blk(256);
    const int rowBlocks = NN / 16;     // 6250

    // wcvt (also zeroes bcur) -> K1 [part1 || gemm0] -> part2 -> F1 -> F2 -> out
    wcvt_kernel<<<64, blk, 0, stream>>>(W0, W1, W2, wf0, wf1, wf2, bcur);
    k1_kernel  <<<P1B + G0B, blk, 0, stream>>>(x, wf0, t0b, erow, ecol, eval, bcur, part, boffs);
    part2_kernel<<<NBUCK, blk, 0, stream>>>(bcur, boffs, part, offs, pce);
    spmm_gemm<128, 1><<<rowBlocks, blk, 0, stream>>>(offs, pce, t0b, wf1, nullptr, t1b, h1b);
    spmm_gemm<64, 2><<<rowBlocks, blk, 0, stream>>>(offs, pce, t1b, wf2, h1b, t0b, nullptr);
    spmm_out<<<rowBlocks, blk, 0, stream>>>(offs, pce, t0b, out);
}